// Round 6
// baseline (657.517 us; speedup 1.0000x reference)
//
#include <hip/hip_runtime.h>
#include <math.h>

#define NPTS 4096
#define NB 2
#define GRID 512

// LDS layout (dynamic shared, SHM_BYTES total)
#define OFF_RED 16384   // eigs_partial reduction 4*32*10*4 = 5120
#define OFF_LM  21504   // maxd2 per-wave maxes
#define OFF_ASH 22528   // BN scale  a_sh[512]
#define OFF_BSH 24576   // BN shift  b_sh[512]
#define OFF_SQ  26624   // gemm stats wn-combine 64*2 floats
#define SHM_BYTES 27136

typedef __attribute__((ext_vector_type(8))) short short8;
typedef __attribute__((ext_vector_type(4))) float f32x4;
typedef unsigned int uint32;

__device__ __forceinline__ unsigned short f2bf(float f) {
  uint32 u = __float_as_uint(f);
  uint32 r = (u + 0x7FFFu + ((u >> 16) & 1u)) >> 16;
  return (unsigned short)r;
}
__device__ __forceinline__ uint2 pack4(float a, float b, float c, float d) {
  uint2 r;
  r.x = (uint32)f2bf(a) | ((uint32)f2bf(b) << 16);
  r.y = (uint32)f2bf(c) | ((uint32)f2bf(d) << 16);
  return r;
}
__device__ __forceinline__ void gload16(const void* g, void* l) {
  __builtin_amdgcn_global_load_lds(
      (const __attribute__((address_space(1))) unsigned int*)g,
      (__attribute__((address_space(3))) unsigned int*)l, 16, 0, 0);
}

struct GemmL {
  const unsigned short* Wp;
  const void* X;            // bf16 (direct) or f32 (fused)
  const float *psIn, *pqIn; // input-layer BN stats slots (fused)
  const float *gam, *bet;   // input-layer BN params (fused)
  const float *aG, *bG;     // precomputed global finalize (L5) or null
  float* Yt;
  float *psO, *pqO;
  int M, Mp, Kp, nTiles;
};

struct KArgs {
  const float *pc, *h1, *h2;
  const float* wsrc[6];
  unsigned short* wp[6];
  unsigned short *h2t, *Zt;
  float *YfA, *YfB;
  float *a4, *b4;
  const float *ew1, *eb1, *ew2, *eb2;
  const float *dgg3, *dgbe3, *g1, *be1, *g3, *be3;
  float* part;
  unsigned int* mx;
  unsigned int* bar;
  float* out;
  GemmL gl[6];
};

// ---------------- device-wide barrier (fresh counter per phase; bar zeroed per launch)
__device__ __forceinline__ void gsync(unsigned int* bar, int ph, int G) {
  __syncthreads();
  if (threadIdx.x == 0) {
    __hip_atomic_fetch_add(&bar[ph], 1u, __ATOMIC_ACQ_REL, __HIP_MEMORY_SCOPE_AGENT);
    int spins = 0;
    while (__hip_atomic_load(&bar[ph], __ATOMIC_ACQUIRE, __HIP_MEMORY_SCOPE_AGENT) <
           (unsigned)G) {
      __builtin_amdgcn_s_sleep(8);
      if (++spins > (1 << 22)) break;  // bail visibly instead of hanging
    }
  }
  __syncthreads();
}

// ---------------- prep helpers ----------------
__device__ void transpose_tile(const float* __restrict__ src, int C,
                               unsigned short* __restrict__ dst, int dstStride, int dstOff,
                               int b, int c0, int n0, char* shm) {
  float(*tile)[33] = (float(*)[33])shm;
  const float* s = src + (size_t)b * C * NPTS;
  int r = threadIdx.x >> 3, q = threadIdx.x & 7;
  float4 v = *(const float4*)(s + (size_t)(c0 + r) * NPTS + n0 + q * 4);
  tile[r][q * 4 + 0] = v.x;
  tile[r][q * 4 + 1] = v.y;
  tile[r][q * 4 + 2] = v.z;
  tile[r][q * 4 + 3] = v.w;
  __syncthreads();
  uint2 o = pack4(tile[q * 4 + 0][r], tile[q * 4 + 1][r], tile[q * 4 + 2][r],
                  tile[q * 4 + 3][r]);
  *(uint2*)(dst + ((size_t)b * NPTS + n0 + r) * dstStride + dstOff + c0 + q * 4) = o;
  __syncthreads();
}

__device__ void ph_prep(const KArgs& A, char* shm, int bid, int G) {
  for (int vb = bid; vb < 9505; vb += G) {
    if (vb < 8192) {
      int b = vb >> 12, r = vb & 4095, ct = r & 31, nt = r >> 5;
      transpose_tile(A.h2, 1024, A.h2t, 1024, 0, b, ct * 32, nt * 32, shm);
    } else if (vb < 9216) {
      int r = vb - 8192, b = r >> 9, r2 = r & 511, ct = r2 & 3, nt = r2 >> 2;
      transpose_tile(A.h1, 128, A.Zt, 192, 0, b, ct * 32, nt * 32, shm);
    } else if (vb < 9248) {
      int r = vb - 9216;
      for (int idx = r * 256 + threadIdx.x; idx < NB * NPTS * 7; idx += 32 * 256) {
        int u = idx % 7, n = (idx / 7) & (NPTS - 1), b = idx / (7 * NPTS);
        *(uint2*)(A.Zt + ((size_t)b * NPTS + n) * 192 + 164 + u * 4) = make_uint2(0u, 0u);
      }
    } else if (vb < 9504) {
      const int segKp[6] = {1024, 256, 64, 192, 512, 256};
      const int segM[6] = {256, 64, 32, 512, 256, 128};
      const int segK[6] = {1024, 256, 64, 164, 512, 256};
      const int segEnd[6] = {262144, 278528, 282624, 380928, 512000, 544768};
      int r = vb - 9248;
      for (int idx = r * 256 + threadIdx.x; idx < 544768; idx += 256 * 256) {
        int w = 0, start = 0;
#pragma unroll
        for (int s = 0; s < 6; ++s)
          if (idx >= segEnd[s]) { w = s + 1; start = segEnd[s]; }
        int local = idx - start, Kp = segKp[w], m = local / Kp, k = local % Kp;
        float v = (m < segM[w] && k < segK[w]) ? A.wsrc[w][m * segK[w] + k] : 0.f;
        A.wp[w][local] = f2bf(v);
      }
    } else {
      if (threadIdx.x < 2) A.mx[threadIdx.x] = 0u;
    }
  }
}

// ---------------- eig: max d2 (one 64i x 512j tile) ----------------
__device__ void ph_eig_max(const KArgs& A, char* shm, int vb) {
  float4* sp = (float4*)shm;       // 512 * 16B
  float* lm = (float*)(shm + OFF_LM);
  int b = vb >> 9, rem = vb & 511, it = rem & 63, jt = rem >> 6;
  int i0 = it * 64, j0 = jt * 512;
  const float* pb = A.pc + (size_t)b * NPTS * 3;
  for (int t = threadIdx.x; t < 512; t += 256) {
    int j = j0 + t;
    sp[t] = make_float4(pb[j * 3], pb[j * 3 + 1], pb[j * 3 + 2], 0.f);
  }
  __syncthreads();
  int il = threadIdx.x & 63, sl = threadIdx.x >> 6;
  int i = i0 + il;
  float xi = pb[i * 3], yi = pb[i * 3 + 1], zi = pb[i * 3 + 2];
  float x2i = xi * xi + yi * yi + zi * zi;
  float m = 0.f;
#pragma unroll 4
  for (int j = sl * 128, e = sl * 128 + 128; j < e; ++j) {
    float4 pj = sp[j];
    float x2j = pj.x * pj.x + pj.y * pj.y + pj.z * pj.z;
    float dot = xi * pj.x + yi * pj.y + zi * pj.z;
    m = fmaxf(m, fmaxf(x2i + x2j - 2.f * dot, 0.f));
  }
#pragma unroll
  for (int off = 32; off > 0; off >>= 1) m = fmaxf(m, __shfl_xor(m, off, 64));
  if ((threadIdx.x & 63) == 0) lm[threadIdx.x >> 6] = m;
  __syncthreads();
  if (threadIdx.x == 0) {
    float v = fmaxf(fmaxf(lm[0], lm[1]), fmaxf(lm[2], lm[3]));
    atomicMax(&A.mx[b], __float_as_uint(v));
  }
  __syncthreads();
}

// ---------------- eig: masked-cov partials (one 32i x 1024j tile) ----------------
__device__ void ph_eig_part(const KArgs& A, char* shm, int vb) {
  float4* sp = (float4*)shm;  // 1024 * 16B
  float(*red)[32][10] = (float(*)[32][10])(shm + OFF_RED);
  int b = vb >> 9, rem = vb & 511, it = rem & 127, js = rem >> 7;
  int i0 = it * 32, j0 = js * 1024;
  const float* pb = A.pc + (size_t)b * NPTS * 3;
  for (int t = threadIdx.x; t < 1024; t += 256) {
    int j = j0 + t;
    sp[t] = make_float4(pb[j * 3], pb[j * 3 + 1], pb[j * 3 + 2], 0.f);
  }
  __syncthreads();
  int il = threadIdx.x & 31, sl = threadIdx.x >> 5;
  int i = i0 + il;
  float xi = pb[i * 3], yi = pb[i * 3 + 1], zi = pb[i * 3 + 2];
  float x2i = xi * xi + yi * yi + zi * zi;
  float r2 = 0.01f * fmaxf(__uint_as_float(A.mx[b]), 1e-12f);
  float vals[10];
#pragma unroll
  for (int v = 0; v < 10; ++v) vals[v] = 0.f;
  int iloc = i - j0;
#pragma unroll 2
  for (int j = sl * 128, e = sl * 128 + 128; j < e; ++j) {
    float4 pj = sp[j];
    float x2j = pj.x * pj.x + pj.y * pj.y + pj.z * pj.z;
    float dot = xi * pj.x + yi * pj.y + zi * pj.z;
    float d2 = fmaxf(fmaxf(x2i + x2j - 2.f * dot, 0.f), 1e-12f);
    float msk = ((d2 < r2) && (j != iloc)) ? 1.f : 0.f;
    vals[0] += msk;
    vals[1] = fmaf(msk, pj.x, vals[1]);
    vals[2] = fmaf(msk, pj.y, vals[2]);
    vals[3] = fmaf(msk, pj.z, vals[3]);
    vals[4] = fmaf(msk, pj.x * pj.x, vals[4]);
    vals[5] = fmaf(msk, pj.x * pj.y, vals[5]);
    vals[6] = fmaf(msk, pj.x * pj.z, vals[6]);
    vals[7] = fmaf(msk, pj.y * pj.y, vals[7]);
    vals[8] = fmaf(msk, pj.y * pj.z, vals[8]);
    vals[9] = fmaf(msk, pj.z * pj.z, vals[9]);
  }
#pragma unroll
  for (int v = 0; v < 10; ++v) vals[v] += __shfl_xor(vals[v], 32, 64);
  int w = threadIdx.x >> 6;
  if ((threadIdx.x & 63) < 32)
#pragma unroll
    for (int v = 0; v < 10; ++v) red[w][il][v] = vals[v];
  __syncthreads();
  if (threadIdx.x < 32) {
    int ii = i0 + threadIdx.x;
    size_t base = ((size_t)(b * 4 + js) * 10) * NPTS + ii;
#pragma unroll
    for (int v = 0; v < 10; ++v)
      A.part[base + (size_t)v * NPTS] = red[0][threadIdx.x][v] + red[1][threadIdx.x][v] +
                                        red[2][threadIdx.x][v] + red[3][threadIdx.x][v];
  }
  __syncthreads();
}

// ---------------- eig: combine -> eigvals -> MLP -> Zt cols 160..163 ----------------
__device__ void ph_eig_fin(const KArgs& A, int vb) {
  int p = vb * 256 + threadIdx.x;
  int b = p >> 12, i = p & (NPTS - 1);
  float t[10];
#pragma unroll
  for (int v = 0; v < 10; ++v) {
    float s = 0.f;
#pragma unroll
    for (int js = 0; js < 4; ++js) s += A.part[((size_t)(b * 4 + js) * 10 + v) * NPTS + i];
    t[v] = s;
  }
  double cntd = (double)t[0];
  double denom = cntd > 1.0 ? cntd : 1.0;
  double mux = t[1] / denom, muy = t[2] / denom, muz = t[3] / denom;
  const double inv_n = 1.0 / (double)NPTS;
  double a00 = ((double)t[4] - cntd * mux * mux) * inv_n;
  double a01 = ((double)t[5] - cntd * mux * muy) * inv_n;
  double a02 = ((double)t[6] - cntd * mux * muz) * inv_n;
  double a11 = ((double)t[7] - cntd * muy * muy) * inv_n;
  double a12 = ((double)t[8] - cntd * muy * muz) * inv_n;
  double a22 = ((double)t[9] - cntd * muz * muz) * inv_n;
  double e0, e1, e2;
  double p1 = a01 * a01 + a02 * a02 + a12 * a12;
  double q = (a00 + a11 + a22) / 3.0;
  double d0 = a00 - q, d1 = a11 - q, d2q = a22 - q;
  double p2 = d0 * d0 + d1 * d1 + d2q * d2q + 2.0 * p1;
  if (p2 <= 1e-30) {
    e0 = e1 = e2 = q;
  } else {
    double pp = sqrt(p2 / 6.0);
    double ip = 1.0 / pp;
    double b00 = d0 * ip, b11 = d1 * ip, b22 = d2q * ip;
    double b01 = a01 * ip, b02 = a02 * ip, b12 = a12 * ip;
    double detB = b00 * (b11 * b22 - b12 * b12) - b01 * (b01 * b22 - b12 * b02) +
                  b02 * (b01 * b12 - b11 * b02);
    double r = detB * 0.5;
    r = r < -1.0 ? -1.0 : (r > 1.0 ? 1.0 : r);
    double phi = acos(r) / 3.0;
    e2 = q + 2.0 * pp * cos(phi);
    e0 = q + 2.0 * pp * cos(phi + 2.0943951023931953);
    e1 = 3.0 * q - e0 - e2;
  }
  float eg[3] = {(float)e0, (float)e1, (float)e2};
  float tmp[4];
#pragma unroll
  for (int e = 0; e < 4; ++e) {
    float v = A.eb1[e];
#pragma unroll
    for (int k = 0; k < 3; ++k) v = fmaf(eg[k], A.ew1[k * 4 + e], v);
    tmp[e] = fmaxf(v, 0.f);
  }
  float h3[4];
#pragma unroll
  for (int f = 0; f < 4; ++f) {
    float v = A.eb2[f];
#pragma unroll
    for (int e = 0; e < 4; ++e) v = fmaf(tmp[e], A.ew2[e * 4 + f], v);
    h3[f] = v;
  }
  *(uint2*)(A.Zt + ((size_t)b * NPTS + i) * 192 + 160) = pack4(h3[0], h3[1], h3[2], h3[3]);
}

// ---------------- in-LDS BN finalize from slots ----------------
__device__ void fin_to_lds(const float* psIn, const float* pqIn, const float* gam,
                           const float* bet, int nch, float* a_sh, float* b_sh) {
  for (int ch = threadIdx.x; ch < nch; ch += 256) {
    const float4* s4 = (const float4*)(psIn + (size_t)ch * 128);
    const float4* q4 = (const float4*)(pqIn + (size_t)ch * 128);
    float s = 0.f, q = 0.f;
#pragma unroll 8
    for (int i = 0; i < 32; ++i) {
      float4 v = s4[i];
      s += v.x + v.y + v.z + v.w;
      float4 w = q4[i];
      q += w.x + w.y + w.z + w.w;
    }
    const float inv = 1.f / 8192.f;
    float mean = s * inv;
    float var = fmaxf(q * inv - mean * mean, 0.f);
    float aa = rsqrtf(var + 1e-5f) * gam[ch];
    a_sh[ch] = aa;
    b_sh[ch] = bet[ch] - mean * aa;
  }
}

// ---------------- GEMM phase: 64Mx64N tiles, BK=64, 4 waves (2m x 2n) ----------------
template <int FUSED>
__device__ void gemm_run(const GemmL& L, char* shm, int bid, int G) {
  if (bid >= L.nTiles) return;
  const int tid = threadIdx.x;
  float* a_sh = (float*)(shm + OFF_ASH);
  float* b_sh = (float*)(shm + OFF_BSH);
  float* sq_sh = (float*)(shm + OFF_SQ);
  char* db = shm;  // 2 x 9216
  if (FUSED) {
    if (L.aG) {
      for (int ch = tid; ch < L.Kp; ch += 256) {
        a_sh[ch] = L.aG[ch];
        b_sh[ch] = L.bG[ch];
      }
    } else {
      fin_to_lds(L.psIn, L.pqIn, L.gam, L.bet, L.Kp, a_sh, b_sh);
    }
    __syncthreads();
  }
  const int lane = tid & 63, wid = tid >> 6;
  const int wm = wid >> 1, wn = wid & 1, g = lane >> 4, c = lane & 15;
  const int ktiles = L.Kp >> 6;
  const int perB = L.nTiles >> 1;

  for (int T = bid; T < L.nTiles; T += G) {
    int b = T / perB, rem = T % perB, mt = rem >> 6, nt = rem & 63;
    int n0 = nt * 64, m0 = mt * 64;
    const unsigned short* Xb = (const unsigned short*)L.X + (size_t)b * NPTS * L.Kp;
    const float* Xfb = (const float*)L.X + (size_t)b * NPTS * L.Kp;

    float4 ld[3][2];
    auto stage_direct = [&](int buf, int kt) {
      int k0 = kt << 6;
#pragma unroll
      for (int i = 0; i < 3; ++i) {
        int u = tid + i * 256;
        if (u < 576) {
          int n = u / 9, r9 = u % 9;
          int k = r9 < 8 ? r9 * 8 : 0;
          gload16(Xb + (size_t)(n0 + n) * L.Kp + k0 + k, db + buf * 9216 + u * 16);
        }
      }
    };
    auto stage_load = [&](int kt) {
      int k0 = kt << 6;
#pragma unroll
      for (int i = 0; i < 3; ++i) {
        int u = tid + i * 256;
        if (u < 576) {
          int n = u / 9, r9 = u % 9;
          if (r9 < 8) {
            const float* s = Xfb + (size_t)(n0 + n) * L.Kp + k0 + r9 * 8;
            ld[i][0] = *(const float4*)s;
            ld[i][1] = *(const float4*)(s + 4);
          }
        }
      }
    };
    auto stage_write = [&](int buf, int kt) {
      int k0 = kt << 6;
#pragma unroll
      for (int i = 0; i < 3; ++i) {
        int u = tid + i * 256;
        if (u < 576) {
          int r9 = u % 9;
          uint4 o = make_uint4(0u, 0u, 0u, 0u);
          if (r9 < 8) {
            int k = k0 + r9 * 8;
            float4 a0 = *(const float4*)&a_sh[k], a1 = *(const float4*)&a_sh[k + 4];
            float4 b0 = *(const float4*)&b_sh[k], b1 = *(const float4*)&b_sh[k + 4];
            uint2 lo = pack4(fmaxf(ld[i][0].x * a0.x + b0.x, 0.f),
                             fmaxf(ld[i][0].y * a0.y + b0.y, 0.f),
                             fmaxf(ld[i][0].z * a0.z + b0.z, 0.f),
                             fmaxf(ld[i][0].w * a0.w + b0.w, 0.f));
            uint2 hi = pack4(fmaxf(ld[i][1].x * a1.x + b1.x, 0.f),
                             fmaxf(ld[i][1].y * a1.y + b1.y, 0.f),
                             fmaxf(ld[i][1].z * a1.z + b1.z, 0.f),
                             fmaxf(ld[i][1].w * a1.w + b1.w, 0.f));
            o = make_uint4(lo.x, lo.y, hi.x, hi.y);
          }
          *(uint4*)(db + buf * 9216 + u * 16) = o;
        }
      }
    };
    auto loadA = [&](int kt, uint4* Af) {
      const unsigned short* base =
          L.Wp + (size_t)(m0 + wm * 32 + c) * L.Kp + (kt << 6) + g * 8;
#pragma unroll
      for (int mf = 0; mf < 2; ++mf)
#pragma unroll
        for (int kw = 0; kw < 2; ++kw)
          Af[mf * 2 + kw] = *(const uint4*)(base + (size_t)mf * 16 * L.Kp + kw * 32);
    };

    f32x4 acc[2][2] = {};
    uint4 Acur[4], Anext[4] = {};
    if (FUSED) {
      stage_load(0);
      stage_write(0, 0);
    } else {
      stage_direct(0, 0);
    }
    loadA(0, Acur);
    __syncthreads();
    int cur = 0;
    for (int t = 0; t < ktiles; ++t) {
      if (t + 1 < ktiles) {
        if (FUSED) stage_load(t + 1);
        else stage_direct(cur ^ 1, t + 1);
        loadA(t + 1, Anext);
      }
#pragma unroll
      for (int kw = 0; kw < 2; ++kw) {
        union { uint4 u; short8 s; } a0, a1;
        a0.u = Acur[0 * 2 + kw];
        a1.u = Acur[1 * 2 + kw];
#pragma unroll
        for (int nf = 0; nf < 2; ++nf) {
          union { uint4 u; short8 s; } bf;
          bf.u = *(const uint4*)(db + cur * 9216 + (wn * 32 + nf * 16 + c) * 144 +
                                 kw * 64 + g * 16);
          acc[0][nf] =
              __builtin_amdgcn_mfma_f32_16x16x32_bf16(a0.s, bf.s, acc[0][nf], 0, 0, 0);
          acc[1][nf] =
              __builtin_amdgcn_mfma_f32_16x16x32_bf16(a1.s, bf.s, acc[1][nf], 0, 0, 0);
        }
      }
      if (FUSED && t + 1 < ktiles) stage_write(cur ^ 1, t + 1);
      __syncthreads();
      cur ^= 1;
#pragma unroll
      for (int i = 0; i < 4; ++i) Acur[i] = Anext[i];
    }

    // C-write: Yt[b][n][m]
#pragma unroll
    for (int nf = 0; nf < 2; ++nf) {
      int n = n0 + wn * 32 + nf * 16 + c;
      float* yrow = L.Yt + ((size_t)b * NPTS + n) * L.Mp;
#pragma unroll
      for (int mf = 0; mf < 2; ++mf) {
        int mb = m0 + wm * 32 + mf * 16 + g * 4;
        *(float4*)(yrow + mb) =
            make_float4(acc[mf][0 + nf][0], acc[mf][nf][1], acc[mf][nf][2], acc[mf][nf][3]);
      }
    }
    // BN partial stats; combine wn pair via LDS -> slot (b*64+nt)
    float sv[2][4], qv[2][4];
#pragma unroll
    for (int mf = 0; mf < 2; ++mf)
#pragma unroll
      for (int r = 0; r < 4; ++r) {
        float s = acc[mf][0][r] + acc[mf][1][r];
        float q = acc[mf][0][r] * acc[mf][0][r] + acc[mf][1][r] * acc[mf][1][r];
#pragma unroll
        for (int m = 1; m < 16; m <<= 1) {
          s += __shfl_xor(s, m, 64);
          q += __shfl_xor(q, m, 64);
        }
        sv[mf][r] = s;
        qv[mf][r] = q;
      }
    if (wn == 1 && c == 0)
#pragma unroll
      for (int mf = 0; mf < 2; ++mf)
#pragma unroll
        for (int r = 0; r < 4; ++r) {
          int row = wm * 32 + mf * 16 + g * 4 + r;
          sq_sh[row * 2 + 0] = sv[mf][r];
          sq_sh[row * 2 + 1] = qv[mf][r];
        }
    __syncthreads();
    if (wn == 0 && c == 0)
#pragma unroll
      for (int mf = 0; mf < 2; ++mf)
#pragma unroll
        for (int r = 0; r < 4; ++r) {
          int row = wm * 32 + mf * 16 + g * 4 + r;
          int gr = m0 + row;
          if (gr < L.M) {
            int slot = b * 64 + nt;
            L.psO[(size_t)gr * 128 + slot] = sv[mf][r] + sq_sh[row * 2 + 0];
            L.pqO[(size_t)gr * 128 + slot] = qv[mf][r] + sq_sh[row * 2 + 1];
          }
        }
    __syncthreads();
  }
}

// ---------------- f2: BN(L3 out)[0..31] -> Zt cols 128..159 ----------------
__device__ void ph_f2(const KArgs& A, char* shm, int bid, int G) {
  if (bid >= 256) return;
  float* a_sh = (float*)(shm + OFF_ASH);
  float* b_sh = (float*)(shm + OFF_BSH);
  fin_to_lds(A.gl[2].psO, A.gl[2].pqO, A.dgg3, A.dgbe3, 32, a_sh, b_sh);
  __syncthreads();
  for (int vb = bid; vb < 256; vb += G) {
    int idx = vb * 256 + threadIdx.x;
    int c4 = idx & 7;
    int n = (idx >> 3) & (NPTS - 1);
    int b = idx >> 15;
    float4 v = *(const float4*)(A.YfA + ((size_t)b * NPTS + n) * 64 + c4 * 4);
    float4 aa = *(const float4*)&a_sh[c4 * 4];
    float4 bb = *(const float4*)&b_sh[c4 * 4];
    uint2 o = pack4(fmaxf(v.x * aa.x + bb.x, 0.f), fmaxf(v.y * aa.y + bb.y, 0.f),
                    fmaxf(v.z * aa.z + bb.z, 0.f), fmaxf(v.w * aa.w + bb.w, 0.f));
    *(uint2*)(A.Zt + ((size_t)b * NPTS + n) * 192 + 128 + c4 * 4) = o;
  }
}

// ---------------- fin4: 512-ch finalize of L4 output -> global a4/b4 ----------------
__device__ void ph_fin4(const KArgs& A, int bid, int G) {
  for (int ch = bid * 256 + threadIdx.x; ch < 512; ch += G * 256) {
    const float4* s4 = (const float4*)(A.gl[3].psO + (size_t)ch * 128);
    const float4* q4 = (const float4*)(A.gl[3].pqO + (size_t)ch * 128);
    float s = 0.f, q = 0.f;
#pragma unroll 8
    for (int i = 0; i < 32; ++i) {
      float4 v = s4[i];
      s += v.x + v.y + v.z + v.w;
      float4 w = q4[i];
      q += w.x + w.y + w.z + w.w;
    }
    const float inv = 1.f / 8192.f;
    float mean = s * inv;
    float var = fmaxf(q * inv - mean * mean, 0.f);
    float aa = rsqrtf(var + 1e-5f) * A.g1[ch];
    A.a4[ch] = aa;
    A.b4[ch] = A.be1[ch] - mean * aa;
  }
}

// ---------------- out: BN+transpose z + xyz copy ----------------
__device__ void ph_out(const KArgs& A, char* shm, int bid, int G) {
  float* a_sh = (float*)(shm + OFF_ASH);
  float* b_sh = (float*)(shm + OFF_BSH);
  fin_to_lds(A.gl[5].psO, A.gl[5].pqO, A.g3, A.be3, 128, a_sh, b_sh);
  __syncthreads();
  float(*tile)[33] = (float(*)[33])shm;
  for (int vb = bid; vb < 1048; vb += G) {
    if (vb < 1024) {
      int b = vb >> 9, r0 = vb & 511;
      int c0 = (r0 & 3) * 32, n0 = (r0 >> 2) * 32;
      int r = threadIdx.x >> 3, q = threadIdx.x & 7;
      float4 v = *(const float4*)(A.YfB + ((size_t)b * NPTS + n0 + r) * 128 + c0 + q * 4);
      float4 aa = *(const float4*)&a_sh[c0 + q * 4];
      float4 bb = *(const float4*)&b_sh[c0 + q * 4];
      tile[r][q * 4 + 0] = fmaxf(v.x * aa.x + bb.x, 0.f);
      tile[r][q * 4 + 1] = fmaxf(v.y * aa.y + bb.y, 0.f);
      tile[r][q * 4 + 2] = fmaxf(v.z * aa.z + bb.z, 0.f);
      tile[r][q * 4 + 3] = fmaxf(v.w * aa.w + bb.w, 0.f);
      __syncthreads();
      float4 o = make_float4(tile[q * 4 + 0][r], tile[q * 4 + 1][r], tile[q * 4 + 2][r],
                             tile[q * 4 + 3][r]);
      float* z = A.out + (size_t)NB * NPTS * 3;
      *(float4*)(z + ((size_t)b * 128 + c0 + r) * NPTS + n0 + q * 4) = o;
      __syncthreads();
    } else {
      int i = (vb - 1024) * 256 + threadIdx.x;
      ((float4*)A.out)[i] = ((const float4*)A.pc)[i];
    }
  }
}

// ---------------- the mega kernel ----------------
__global__ void __launch_bounds__(256, 2) mega(KArgs A) {
  extern __shared__ char shm[];
  int bid = blockIdx.x, G = gridDim.x;
  unsigned int* bar = A.bar;

  ph_prep(A, shm, bid, G);                    // Ph0
  gsync(bar, 0, G);
  gemm_run<0>(A.gl[0], shm, bid, G);          // Ph1: L1
  for (int vb = bid; vb < 1024; vb += G) ph_eig_max(A, shm, vb);
  gsync(bar, 1, G);
  gemm_run<1>(A.gl[1], shm, bid, G);          // Ph2: L2 (fin L1 in-block)
  for (int vb = bid; vb < 1024; vb += G) ph_eig_part(A, shm, vb);
  gsync(bar, 2, G);
  gemm_run<1>(A.gl[2], shm, bid, G);          // Ph3: L3 (fin L2)
  for (int vb = bid; vb < 32; vb += G) ph_eig_fin(A, vb);
  gsync(bar, 3, G);
  ph_f2(A, shm, bid, G);                      // Ph4: f2 (fin L3)
  gsync(bar, 4, G);
  gemm_run<0>(A.gl[3], shm, bid, G);          // Ph5: L4 (direct Zt)
  gsync(bar, 5, G);
  ph_fin4(A, bid, G);                         // Ph6: fin L4 -> global
  gsync(bar, 6, G);
  gemm_run<1>(A.gl[4], shm, bid, G);          // Ph7: L5 (a4/b4 copy)
  gsync(bar, 7, G);
  gemm_run<1>(A.gl[5], shm, bid, G);          // Ph8: L6 (fin L5)
  gsync(bar, 8, G);
  ph_out(A, shm, bid, G);                     // Ph9
}

extern "C" void kernel_launch(void* const* d_in, const int* in_sizes, int n_in,
                              void* d_out, int out_size, void* d_ws, size_t ws_size,
                              hipStream_t stream) {
  (void)in_sizes; (void)n_in; (void)out_size; (void)ws_size;
  KArgs A;
  A.pc = (const float*)d_in[0];
  A.h1 = (const float*)d_in[1];
  A.h2 = (const float*)d_in[2];
  const float* dgw1 = (const float*)d_in[3];
  const float* dgg1 = (const float*)d_in[5];
  const float* dgbe1 = (const float*)d_in[6];
  const float* dgw2 = (const float*)d_in[7];
  const float* dgg2 = (const float*)d_in[9];
  const float* dgbe2 = (const float*)d_in[10];
  const float* dgw3 = (const float*)d_in[11];
  A.dgg3 = (const float*)d_in[13];
  A.dgbe3 = (const float*)d_in[14];
  A.ew1 = (const float*)d_in[15];
  A.eb1 = (const float*)d_in[16];
  A.ew2 = (const float*)d_in[17];
  A.eb2 = (const float*)d_in[18];
  const float* w1 = (const float*)d_in[19];
  A.g1 = (const float*)d_in[21];
  A.be1 = (const float*)d_in[22];
  const float* w2 = (const float*)d_in[23];
  const float* g2 = (const float*)d_in[25];
  const float* be2 = (const float*)d_in[26];
  const float* w3 = (const float*)d_in[27];
  A.g3 = (const float*)d_in[29];
  A.be3 = (const float*)d_in[30];
  A.out = (float*)d_out;

  // workspace
  char* p = (char*)d_ws;
  auto take = [&](size_t bytes) { char* r = p; p += (bytes + 255) & ~(size_t)255; return r; };
  A.h2t = (unsigned short*)take((size_t)NB * NPTS * 1024 * 2);
  A.Zt = (unsigned short*)take((size_t)NB * NPTS * 192 * 2);
  A.wp[0] = (unsigned short*)take((size_t)256 * 1024 * 2);
  A.wp[1] = (unsigned short*)take((size_t)64 * 256 * 2);
  A.wp[2] = (unsigned short*)take((size_t)64 * 64 * 2);
  A.wp[3] = (unsigned short*)take((size_t)512 * 192 * 2);
  A.wp[4] = (unsigned short*)take((size_t)256 * 512 * 2);
  A.wp[5] = (unsigned short*)take((size_t)128 * 256 * 2);
  A.YfA = (float*)take((size_t)NB * NPTS * 256 * 4);
  A.YfB = (float*)take((size_t)NB * NPTS * 512 * 4);
  float* ps[6];
  float* pq[6];
  for (int i = 0; i < 6; ++i) {
    ps[i] = (float*)take((size_t)512 * 128 * 4);
    pq[i] = (float*)take((size_t)512 * 128 * 4);
  }
  A.a4 = (float*)take(512 * 4);
  A.b4 = (float*)take(512 * 4);
  A.part = (float*)take((size_t)NB * 4 * 10 * NPTS * 4);
  A.mx = (unsigned int*)take(256);
  A.bar = (unsigned int*)take(256);

  A.wsrc[0] = dgw1; A.wsrc[1] = dgw2; A.wsrc[2] = dgw3;
  A.wsrc[3] = w1;   A.wsrc[4] = w2;   A.wsrc[5] = w3;

  GemmL* gl = A.gl;
  // L1: h2t(bf16) -> YfA ; stats ps0
  gl[0] = {A.wp[0], A.h2t, nullptr, nullptr, nullptr, nullptr, nullptr, nullptr,
           A.YfA, ps[0], pq[0], 256, 256, 1024, 512};
  // L2: BN(YfA; ps0,dgg1) -> YfB ; stats ps1
  gl[1] = {A.wp[1], A.YfA, ps[0], pq[0], dgg1, dgbe1, nullptr, nullptr,
           A.YfB, ps[1], pq[1], 64, 64, 256, 128};
  // L3: BN(YfB; ps1,dgg2) -> YfA ; stats ps2
  gl[2] = {A.wp[2], A.YfB, ps[1], pq[1], dgg2, dgbe2, nullptr, nullptr,
           A.YfA, ps[2], pq[2], 32, 64, 64, 128};
  // L4: Zt(bf16) -> YfB ; stats ps3
  gl[3] = {A.wp[3], A.Zt, nullptr, nullptr, nullptr, nullptr, nullptr, nullptr,
           A.YfB, ps[3], pq[3], 512, 512, 192, 1024};
  // L5: BN(YfB; a4/b4 global) -> YfA ; stats ps4
  gl[4] = {A.wp[4], A.YfB, nullptr, nullptr, nullptr, nullptr, A.a4, A.b4,
           A.YfA, ps[4], pq[4], 256, 256, 512, 512};
  // L6: BN(YfA; ps4,g2) -> YfB ; stats ps5
  gl[5] = {A.wp[5], A.YfA, ps[4], pq[4], g2, be2, nullptr, nullptr,
           A.YfB, ps[5], pq[5], 128, 128, 256, 256};

  hipMemsetAsync(A.bar, 0, 256, stream);
  mega<<<GRID, 256, SHM_BYTES, stream>>>(A);
}

// Round 7
// 168.352 us; speedup vs baseline: 3.9056x; 3.9056x over previous
//
#include <hip/hip_runtime.h>
#include <math.h>

#define NPTS 4096
#define NB 2

typedef __attribute__((ext_vector_type(8))) short short8;
typedef __attribute__((ext_vector_type(4))) float f32x4;
typedef unsigned int uint32;

__device__ __forceinline__ unsigned short f2bf(float f) {
  uint32 u = __float_as_uint(f);
  uint32 r = (u + 0x7FFFu + ((u >> 16) & 1u)) >> 16;
  return (unsigned short)r;
}
__device__ __forceinline__ uint2 pack4(float a, float b, float c, float d) {
  uint2 r;
  r.x = (uint32)f2bf(a) | ((uint32)f2bf(b) << 16);
  r.y = (uint32)f2bf(c) | ((uint32)f2bf(d) << 16);
  return r;
}
__device__ __forceinline__ float bflo(uint32 w) { return __uint_as_float((w & 0xffffu) << 16); }
__device__ __forceinline__ float bfhi(uint32 w) { return __uint_as_float(w & 0xffff0000u); }

struct WArgs {
  const float* src[6];
  unsigned short* dst[6];
};

// ---------------- transpose tile helper: src[b][C][4096] f32 -> dst[b][n][dstOff+c] bf16
__device__ __forceinline__ void transpose_tile(const float* __restrict__ src, int C,
                                               unsigned short* __restrict__ dst,
                                               int dstStride, int dstOff, int b, int c0,
                                               int n0) {
  __shared__ float tile[32][33];
  const float* s = src + (size_t)b * C * NPTS;
  int r = threadIdx.x >> 3, q = threadIdx.x & 7;
  float4 v = *(const float4*)(s + (size_t)(c0 + r) * NPTS + n0 + q * 4);
  tile[r][q * 4 + 0] = v.x;
  tile[r][q * 4 + 1] = v.y;
  tile[r][q * 4 + 2] = v.z;
  tile[r][q * 4 + 3] = v.w;
  __syncthreads();
  uint2 o = pack4(tile[q * 4 + 0][r], tile[q * 4 + 1][r], tile[q * 4 + 2][r],
                  tile[q * 4 + 3][r]);
  *(uint2*)(dst + ((size_t)b * NPTS + n0 + r) * dstStride + dstOff + c0 + q * 4) = o;
}

// ---------------- mega prep (as R5): h2 transpose, h1->Zt, pads, weights, mx init ----
__global__ __launch_bounds__(256)
void prep_all(const float* __restrict__ h2, const float* __restrict__ h1, WArgs wa,
              unsigned short* __restrict__ h2t, unsigned short* __restrict__ Zt,
              unsigned int* __restrict__ mx) {
  int bid = blockIdx.x;
  if (bid < 8192) {
    int b = bid >> 12, r = bid & 4095, ct = r & 31, nt = r >> 5;
    transpose_tile(h2, 1024, h2t, 1024, 0, b, ct * 32, nt * 32);
  } else if (bid < 9216) {
    int r = bid - 8192, b = r >> 9, r2 = r & 511, ct = r2 & 3, nt = r2 >> 2;
    transpose_tile(h1, 128, Zt, 192, 0, b, ct * 32, nt * 32);
  } else if (bid < 9248) {
    int r = bid - 9216;
    for (int idx = r * 256 + threadIdx.x; idx < NB * NPTS * 7; idx += 32 * 256) {
      int u = idx % 7, n = (idx / 7) & (NPTS - 1), b = idx / (7 * NPTS);
      *(uint2*)(Zt + ((size_t)b * NPTS + n) * 192 + 164 + u * 4) = make_uint2(0u, 0u);
    }
  } else if (bid < 9504) {
    const int segKp[6] = {1024, 256, 64, 192, 512, 256};
    const int segM[6] = {256, 64, 32, 512, 256, 128};
    const int segK[6] = {1024, 256, 64, 164, 512, 256};
    const int segEnd[6] = {262144, 278528, 282624, 380928, 512000, 544768};
    int r = bid - 9248;
    for (int idx = r * 256 + threadIdx.x; idx < 544768; idx += 256 * 256) {
      int w = 0, start = 0;
#pragma unroll
      for (int s = 0; s < 6; ++s)
        if (idx >= segEnd[s]) { w = s + 1; start = segEnd[s]; }
      int local = idx - start, Kp = segKp[w], m = local / Kp, k = local % Kp;
      float v = (m < segM[w] && k < segK[w]) ? wa.src[w][m * segK[w] + k] : 0.f;
      wa.dst[w][local] = f2bf(v);
    }
  } else {
    if (threadIdx.x < 2) mx[threadIdx.x] = 0u;
  }
}

// ---------------- MFMA GEMM: Y[b][n][m] (bf16 raw) = sum_k Wp[m][k] * bn(X[b][n][k])
// tile 64M x 64N, BK=64, 4 waves (2m x 2n). Reg-staged global->reg->LDS double buffer:
// loads for k-tile t+1 issue before MFMA(t); syncthreads only drains ds_writes.
// BN_IN: input X is raw bf16 y of prev layer; apply a*x+b, relu during staging.
// Stats: per-channel (sum, sumsq) partials to slot (b*128 + nt*2 + wn).
template <int BN_IN>
__global__ __launch_bounds__(256)
void gemm_mfma_t(const unsigned short* __restrict__ Wp, const unsigned short* __restrict__ X,
                 const float* __restrict__ aG, const float* __restrict__ bG,
                 unsigned short* __restrict__ Y, float* __restrict__ psum,
                 float* __restrict__ psq, int M, int Mp, int Kp) {
  __shared__ char db[2][9216];  // 64 rows x 144B, x2
  __shared__ float a_sh[512], b_sh[512];
  const int b = blockIdx.z, nt = blockIdx.x, mt = blockIdx.y;
  const int n0 = nt * 64, m0 = mt * 64;
  const int tid = threadIdx.x, lane = tid & 63, wid = tid >> 6;
  const int wm = wid >> 1, wn = wid & 1, g = lane >> 4, c = lane & 15;
  const int ktiles = Kp >> 6;
  const unsigned short* Xb = X + (size_t)b * NPTS * Kp;

  if (BN_IN) {
    for (int ch = tid; ch < Kp; ch += 256) {
      a_sh[ch] = aG[ch];
      b_sh[ch] = bG[ch];
    }
    __syncthreads();
  }

  uint4 st[2];
  auto loadG = [&](int kt) {
    int k0 = kt << 6;
#pragma unroll
    for (int i = 0; i < 2; ++i) {
      int u = tid + i * 256, n = u >> 3, s = u & 7;
      st[i] = *(const uint4*)(Xb + (size_t)(n0 + n) * Kp + k0 + s * 8);
    }
  };
  auto writeS = [&](int buf, int kt) {
    int k0 = kt << 6;
#pragma unroll
    for (int i = 0; i < 2; ++i) {
      int u = tid + i * 256, n = u >> 3, s = u & 7;
      uint4 v = st[i];
      if (BN_IN) {
        int k = k0 + s * 8;
        float4 a0 = *(const float4*)&a_sh[k], a1 = *(const float4*)&a_sh[k + 4];
        float4 b0 = *(const float4*)&b_sh[k], b1 = *(const float4*)&b_sh[k + 4];
        uint2 lo = pack4(fmaxf(bflo(v.x) * a0.x + b0.x, 0.f),
                         fmaxf(bfhi(v.x) * a0.y + b0.y, 0.f),
                         fmaxf(bflo(v.y) * a0.z + b0.z, 0.f),
                         fmaxf(bfhi(v.y) * a0.w + b0.w, 0.f));
        uint2 hi = pack4(fmaxf(bflo(v.z) * a1.x + b1.x, 0.f),
                         fmaxf(bfhi(v.z) * a1.y + b1.y, 0.f),
                         fmaxf(bflo(v.w) * a1.z + b1.z, 0.f),
                         fmaxf(bfhi(v.w) * a1.w + b1.w, 0.f));
        v = make_uint4(lo.x, lo.y, hi.x, hi.y);
      }
      *(uint4*)&db[buf][u / 8 * 144 + (u & 7) * 16] = v;
      (void)n;
    }
  };
  auto loadA = [&](int kt, uint4* Af) {
    const unsigned short* base = Wp + (size_t)(m0 + wm * 32 + c) * Kp + (kt << 6) + g * 8;
#pragma unroll
    for (int mf = 0; mf < 2; ++mf)
#pragma unroll
      for (int kw = 0; kw < 2; ++kw)
        Af[mf * 2 + kw] = *(const uint4*)(base + (size_t)mf * 16 * Kp + kw * 32);
  };

  f32x4 acc[2][2] = {};
  uint4 Acur[4], Anext[4] = {};
  loadG(0);
  loadA(0, Acur);
  writeS(0, 0);
  __syncthreads();
  int cur = 0;
  for (int t = 0; t < ktiles; ++t) {
    if (t + 1 < ktiles) {
      loadG(t + 1);
      loadA(t + 1, Anext);
    }
#pragma unroll
    for (int kw = 0; kw < 2; ++kw) {
      union { uint4 u; short8 s; } a0, a1;
      a0.u = Acur[0 * 2 + kw];
      a1.u = Acur[1 * 2 + kw];
#pragma unroll
      for (int nf = 0; nf < 2; ++nf) {
        union { uint4 u; short8 s; } bf;
        bf.u = *(const uint4*)&db[cur][(wn * 32 + nf * 16 + c) * 144 + kw * 64 + g * 16];
        acc[0][nf] = __builtin_amdgcn_mfma_f32_16x16x32_bf16(a0.s, bf.s, acc[0][nf], 0, 0, 0);
        acc[1][nf] = __builtin_amdgcn_mfma_f32_16x16x32_bf16(a1.s, bf.s, acc[1][nf], 0, 0, 0);
      }
    }
    if (t + 1 < ktiles) writeS(cur ^ 1, t + 1);
    __syncthreads();
    cur ^= 1;
#pragma unroll
    for (int i = 0; i < 4; ++i) Acur[i] = Anext[i];
  }

  // C-write (bf16 raw): row m = m0+wm*32+mf*16+g*4+r, col n = n0+wn*32+nf*16+c
#pragma unroll
  for (int nf = 0; nf < 2; ++nf) {
    int n = n0 + wn * 32 + nf * 16 + c;
    unsigned short* yrow = Y + ((size_t)b * NPTS + n) * Mp;
#pragma unroll
    for (int mf = 0; mf < 2; ++mf) {
      int mb = m0 + wm * 32 + mf * 16 + g * 4;
      *(uint2*)(yrow + mb) =
          pack4(acc[mf][nf][0], acc[mf][nf][1], acc[mf][nf][2], acc[mf][nf][3]);
    }
  }
  // BN partials (f32, pre-rounding): sum over this wave's 32 n; slot b*128+nt*2+wn
  int slot = b * 128 + nt * 2 + wn;
#pragma unroll
  for (int mf = 0; mf < 2; ++mf)
#pragma unroll
    for (int r = 0; r < 4; ++r) {
      float s = acc[mf][0][r] + acc[mf][1][r];
      float q = acc[mf][0][r] * acc[mf][0][r] + acc[mf][1][r] * acc[mf][1][r];
#pragma unroll
      for (int m = 1; m < 16; m <<= 1) {
        s += __shfl_xor(s, m, 64);
        q += __shfl_xor(q, m, 64);
      }
      int row = m0 + wm * 32 + mf * 16 + g * 4 + r;
      if (c == 0 && row < M) {
        psum[(size_t)row * 256 + slot] = s;
        psq[(size_t)row * 256 + slot] = q;
      }
    }
}

// ---------------- BN finalize: 256 slots -> a_[ch], b_[ch] ----------------
__global__ __launch_bounds__(256)
void bn_finalize(const float* __restrict__ psum, const float* __restrict__ psq,
                 const float* __restrict__ gamma, const float* __restrict__ beta,
                 float* __restrict__ a_, float* __restrict__ b_) {
  int ch = blockIdx.x, t = threadIdx.x;
  float s = psum[(size_t)ch * 256 + t];
  float q = psq[(size_t)ch * 256 + t];
#pragma unroll
  for (int m = 1; m < 64; m <<= 1) {
    s += __shfl_xor(s, m, 64);
    q += __shfl_xor(q, m, 64);
  }
  __shared__ float ws[4][2];
  if ((t & 63) == 0) { ws[t >> 6][0] = s; ws[t >> 6][1] = q; }
  __syncthreads();
  if (t == 0) {
    float S = ws[0][0] + ws[1][0] + ws[2][0] + ws[3][0];
    float Q = ws[0][1] + ws[1][1] + ws[2][1] + ws[3][1];
    const float inv = 1.f / (float)(NB * NPTS);
    float mean = S * inv;
    float var = fmaxf(Q * inv - mean * mean, 0.f);
    float aa = rsqrtf(var + 1e-5f) * gamma[ch];
    a_[ch] = aa;
    b_[ch] = beta[ch] - mean * aa;
  }
}

// ---------------- f2: BN(y3 raw bf16)[0..31] -> Zt cols 128..159 ----------------
__global__ __launch_bounds__(256)
void f2_apply(const unsigned short* __restrict__ Y, const float* __restrict__ a_,
              const float* __restrict__ b_, unsigned short* __restrict__ Zt) {
  int idx = blockIdx.x * 256 + threadIdx.x;  // NB*NPTS*8
  int c4 = idx & 7;
  int n = (idx >> 3) & (NPTS - 1);
  int b = idx >> 15;
  uint2 v = *(const uint2*)(Y + ((size_t)b * NPTS + n) * 64 + c4 * 4);
  float4 aa = ((const float4*)a_)[c4];
  float4 bb = ((const float4*)b_)[c4];
  uint2 o = pack4(fmaxf(bflo(v.x) * aa.x + bb.x, 0.f), fmaxf(bfhi(v.x) * aa.y + bb.y, 0.f),
                  fmaxf(bflo(v.y) * aa.z + bb.z, 0.f), fmaxf(bfhi(v.y) * aa.w + bb.w, 0.f));
  *(uint2*)(Zt + ((size_t)b * NPTS + n) * 192 + 128 + c4 * 4) = o;
}

// ---------------- final out: BN+transpose z from y6 (bf16 raw), + xyz copy -----------
__global__ __launch_bounds__(256)
void out_final(const unsigned short* __restrict__ Y, const float* __restrict__ a_,
               const float* __restrict__ b_, const float* __restrict__ pc,
               float* __restrict__ out) {
  int bid = blockIdx.x;
  if (bid < 1024) {
    __shared__ float tile[32][33];
    int b = bid >> 9, r0 = bid & 511;
    int c0 = (r0 & 3) * 32, n0 = (r0 >> 2) * 32;
    int r = threadIdx.x >> 3, q = threadIdx.x & 7;
    uint2 v = *(const uint2*)(Y + ((size_t)b * NPTS + n0 + r) * 128 + c0 + q * 4);
    float4 aa = *(const float4*)(a_ + c0 + q * 4);
    float4 bb = *(const float4*)(b_ + c0 + q * 4);
    tile[r][q * 4 + 0] = fmaxf(bflo(v.x) * aa.x + bb.x, 0.f);
    tile[r][q * 4 + 1] = fmaxf(bfhi(v.x) * aa.y + bb.y, 0.f);
    tile[r][q * 4 + 2] = fmaxf(bflo(v.y) * aa.z + bb.z, 0.f);
    tile[r][q * 4 + 3] = fmaxf(bfhi(v.y) * aa.w + bb.w, 0.f);
    __syncthreads();
    float4 o = make_float4(tile[q * 4 + 0][r], tile[q * 4 + 1][r], tile[q * 4 + 2][r],
                           tile[q * 4 + 3][r]);
    float* z = out + (size_t)NB * NPTS * 3;
    *(float4*)(z + ((size_t)b * 128 + c0 + r) * NPTS + n0 + q * 4) = o;
  } else {
    int i = (bid - 1024) * 256 + threadIdx.x;
    ((float4*)out)[i] = ((const float4*)pc)[i];
  }
}

// ---------------- eig pass 1: per-batch max d2, j-sliced (as R5) ----------------
__global__ __launch_bounds__(256)
void maxd2_kernel(const float* __restrict__ pc, unsigned int* __restrict__ mx) {
  __shared__ float4 sp[512];
  __shared__ float lm[4];
  int b = blockIdx.z;
  int j0 = blockIdx.y * 512;
  int i0 = blockIdx.x * 64;
  const float* pb = pc + (size_t)b * NPTS * 3;
  for (int t = threadIdx.x; t < 512; t += 256) {
    int j = j0 + t;
    sp[t] = make_float4(pb[j * 3], pb[j * 3 + 1], pb[j * 3 + 2], 0.f);
  }
  __syncthreads();
  int il = threadIdx.x & 63, sl = threadIdx.x >> 6;
  int i = i0 + il;
  float xi = pb[i * 3], yi = pb[i * 3 + 1], zi = pb[i * 3 + 2];
  float x2i = xi * xi + yi * yi + zi * zi;
  float m = 0.f;
#pragma unroll 4
  for (int j = sl * 128, e = sl * 128 + 128; j < e; ++j) {
    float4 pj = sp[j];
    float x2j = pj.x * pj.x + pj.y * pj.y + pj.z * pj.z;
    float dot = xi * pj.x + yi * pj.y + zi * pj.z;
    m = fmaxf(m, fmaxf(x2i + x2j - 2.f * dot, 0.f));
  }
#pragma unroll
  for (int off = 32; off > 0; off >>= 1) m = fmaxf(m, __shfl_xor(m, off, 64));
  if ((threadIdx.x & 63) == 0) lm[threadIdx.x >> 6] = m;
  __syncthreads();
  if (threadIdx.x == 0) {
    float v = fmaxf(fmaxf(lm[0], lm[1]), fmaxf(lm[2], lm[3]));
    atomicMax(&mx[b], __float_as_uint(v));
  }
}

// ---------------- eig pass 2a: masked-cov partials (as R5) ----------------
__global__ __launch_bounds__(256)
void eigs_partial(const float* __restrict__ pc, const unsigned int* __restrict__ mx,
                  float* __restrict__ part) {
  __shared__ float4 sp[1024];
  __shared__ float red[4][32][10];
  int b = blockIdx.z;
  int js = blockIdx.y;
  int j0 = js * 1024;
  int i0 = blockIdx.x * 32;
  const float* pb = pc + (size_t)b * NPTS * 3;
  for (int t = threadIdx.x; t < 1024; t += 256) {
    int j = j0 + t;
    sp[t] = make_float4(pb[j * 3], pb[j * 3 + 1], pb[j * 3 + 2], 0.f);
  }
  __syncthreads();
  int il = threadIdx.x & 31, sl = threadIdx.x >> 5;
  int i = i0 + il;
  float xi = pb[i * 3], yi = pb[i * 3 + 1], zi = pb[i * 3 + 2];
  float x2i = xi * xi + yi * yi + zi * zi;
  float r2 = 0.01f * fmaxf(__uint_as_float(mx[b]), 1e-12f);
  float vals[10];
#pragma unroll
  for (int v = 0; v < 10; ++v) vals[v] = 0.f;
  int iloc = i - j0;
#pragma unroll 2
  for (int j = sl * 128, e = sl * 128 + 128; j < e; ++j) {
    float4 pj = sp[j];
    float x2j = pj.x * pj.x + pj.y * pj.y + pj.z * pj.z;
    float dot = xi * pj.x + yi * pj.y + zi * pj.z;
    float d2 = fmaxf(fmaxf(x2i + x2j - 2.f * dot, 0.f), 1e-12f);
    float msk = ((d2 < r2) && (j != iloc)) ? 1.f : 0.f;
    vals[0] += msk;
    vals[1] = fmaf(msk, pj.x, vals[1]);
    vals[2] = fmaf(msk, pj.y, vals[2]);
    vals[3] = fmaf(msk, pj.z, vals[3]);
    vals[4] = fmaf(msk, pj.x * pj.x, vals[4]);
    vals[5] = fmaf(msk, pj.x * pj.y, vals[5]);
    vals[6] = fmaf(msk, pj.x * pj.z, vals[6]);
    vals[7] = fmaf(msk, pj.y * pj.y, vals[7]);
    vals[8] = fmaf(msk, pj.y * pj.z, vals[8]);
    vals[9] = fmaf(msk, pj.z * pj.z, vals[9]);
  }
#pragma unroll
  for (int v = 0; v < 10; ++v) vals[v] += __shfl_xor(vals[v], 32, 64);
  int w = threadIdx.x >> 6;
  if ((threadIdx.x & 63) < 32)
#pragma unroll
    for (int v = 0; v < 10; ++v) red[w][il][v] = vals[v];
  __syncthreads();
  if (threadIdx.x < 32) {
    int ii = i0 + threadIdx.x;
    size_t base = ((size_t)(b * 4 + js) * 10) * NPTS + ii;
#pragma unroll
    for (int v = 0; v < 10; ++v)
      part[base + (size_t)v * NPTS] = red[0][threadIdx.x][v] + red[1][threadIdx.x][v] +
                                      red[2][threadIdx.x][v] + red[3][threadIdx.x][v];
  }
}

// ---------------- eig pass 2b: combine -> eigvals -> MLP -> Zt (as R5) ----------------
__global__ __launch_bounds__(256)
void eigs_finalize(const float* __restrict__ part, const float* __restrict__ ew1,
                   const float* __restrict__ eb1, const float* __restrict__ ew2,
                   const float* __restrict__ eb2, unsigned short* __restrict__ Zt) {
  int p = blockIdx.x * 256 + threadIdx.x;
  int b = p >> 12, i = p & (NPTS - 1);
  float t[10];
#pragma unroll
  for (int v = 0; v < 10; ++v) {
    float s = 0.f;
#pragma unroll
    for (int js = 0; js < 4; ++js) s += part[((size_t)(b * 4 + js) * 10 + v) * NPTS + i];
    t[v] = s;
  }
  double cntd = (double)t[0];
  double denom = cntd > 1.0 ? cntd : 1.0;
  double mux = t[1] / denom, muy = t[2] / denom, muz = t[3] / denom;
  const double inv_n = 1.0 / (double)NPTS;
  double a00 = ((double)t[4] - cntd * mux * mux) * inv_n;
  double a01 = ((double)t[5] - cntd * mux * muy) * inv_n;
  double a02 = ((double)t[6] - cntd * mux * muz) * inv_n;
  double a11 = ((double)t[7] - cntd * muy * muy) * inv_n;
  double a12 = ((double)t[8] - cntd * muy * muz) * inv_n;
  double a22 = ((double)t[9] - cntd * muz * muz) * inv_n;
  double e0, e1, e2;
  double p1 = a01 * a01 + a02 * a02 + a12 * a12;
  double q = (a00 + a11 + a22) / 3.0;
  double d0 = a00 - q, d1 = a11 - q, d2q = a22 - q;
  double p2 = d0 * d0 + d1 * d1 + d2q * d2q + 2.0 * p1;
  if (p2 <= 1e-30) {
    e0 = e1 = e2 = q;
  } else {
    double pp = sqrt(p2 / 6.0);
    double ip = 1.0 / pp;
    double b00 = d0 * ip, b11 = d1 * ip, b22 = d2q * ip;
    double b01 = a01 * ip, b02 = a02 * ip, b12 = a12 * ip;
    double detB = b00 * (b11 * b22 - b12 * b12) - b01 * (b01 * b22 - b12 * b02) +
                  b02 * (b01 * b12 - b11 * b02);
    double r = detB * 0.5;
    r = r < -1.0 ? -1.0 : (r > 1.0 ? 1.0 : r);
    double phi = acos(r) / 3.0;
    e2 = q + 2.0 * pp * cos(phi);
    e0 = q + 2.0 * pp * cos(phi + 2.0943951023931953);
    e1 = 3.0 * q - e0 - e2;
  }
  float eg[3] = {(float)e0, (float)e1, (float)e2};
  float tmp[4];
#pragma unroll
  for (int e = 0; e < 4; ++e) {
    float v = eb1[e];
#pragma unroll
    for (int k = 0; k < 3; ++k) v = fmaf(eg[k], ew1[k * 4 + e], v);
    tmp[e] = fmaxf(v, 0.f);
  }
  float h3[4];
#pragma unroll
  for (int f = 0; f < 4; ++f) {
    float v = eb2[f];
#pragma unroll
    for (int e = 0; e < 4; ++e) v = fmaf(tmp[e], ew2[e * 4 + f], v);
    h3[f] = v;
  }
  *(uint2*)(Zt + ((size_t)b * NPTS + i) * 192 + 160) = pack4(h3[0], h3[1], h3[2], h3[3]);
}

extern "C" void kernel_launch(void* const* d_in, const int* in_sizes, int n_in,
                              void* d_out, int out_size, void* d_ws, size_t ws_size,
                              hipStream_t stream) {
  (void)in_sizes; (void)n_in; (void)out_size; (void)ws_size;
  const float* pc    = (const float*)d_in[0];
  const float* h1    = (const float*)d_in[1];
  const float* h2    = (const float*)d_in[2];
  const float* dgw1  = (const float*)d_in[3];
  const float* dgg1  = (const float*)d_in[5];
  const float* dgbe1 = (const float*)d_in[6];
  const float* dgw2  = (const float*)d_in[7];
  const float* dgg2  = (const float*)d_in[9];
  const float* dgbe2 = (const float*)d_in[10];
  const float* dgw3  = (const float*)d_in[11];
  const float* dgg3  = (const float*)d_in[13];
  const float* dgbe3 = (const float*)d_in[14];
  const float* ew1   = (const float*)d_in[15];
  const float* eb1   = (const float*)d_in[16];
  const float* ew2   = (const float*)d_in[17];
  const float* eb2   = (const float*)d_in[18];
  const float* w1    = (const float*)d_in[19];
  const float* g1    = (const float*)d_in[21];
  const float* be1   = (const float*)d_in[22];
  const float* w2    = (const float*)d_in[23];
  const float* g2    = (const float*)d_in[25];
  const float* be2   = (const float*)d_in[26];
  const float* w3    = (const float*)d_in[27];
  const float* g3    = (const float*)d_in[29];
  const float* be3   = (const float*)d_in[30];
  float* out = (float*)d_out;

  // ---- workspace ----
  char* p = (char*)d_ws;
  auto take = [&](size_t bytes) { char* r = p; p += (bytes + 255) & ~(size_t)255; return r; };
  unsigned short* h2t = (unsigned short*)take((size_t)NB * NPTS * 1024 * 2);
  unsigned short* Zt  = (unsigned short*)take((size_t)NB * NPTS * 192 * 2);
  unsigned short* wp1 = (unsigned short*)take((size_t)256 * 1024 * 2);
  unsigned short* wp2 = (unsigned short*)take((size_t)64 * 256 * 2);
  unsigned short* wp3 = (unsigned short*)take((size_t)64 * 64 * 2);
  unsigned short* wp4 = (unsigned short*)take((size_t)512 * 192 * 2);
  unsigned short* wp5 = (unsigned short*)take((size_t)256 * 512 * 2);
  unsigned short* wp6 = (unsigned short*)take((size_t)128 * 256 * 2);
  unsigned short* yA  = (unsigned short*)take((size_t)NB * NPTS * 256 * 2);
  unsigned short* yB  = (unsigned short*)take((size_t)NB * NPTS * 512 * 2);
  float* psum = (float*)take((size_t)512 * 256 * 4);
  float* psq  = (float*)take((size_t)512 * 256 * 4);
  float* a_   = (float*)take((size_t)512 * 4);
  float* b_   = (float*)take((size_t)512 * 4);
  float* part = (float*)take((size_t)NB * 4 * 10 * NPTS * 4);
  unsigned int* mx = (unsigned int*)take(256);

  WArgs wa;
  wa.src[0] = dgw1; wa.dst[0] = wp1;
  wa.src[1] = dgw2; wa.dst[1] = wp2;
  wa.src[2] = dgw3; wa.dst[2] = wp3;
  wa.src[3] = w1;   wa.dst[3] = wp4;
  wa.src[4] = w2;   wa.dst[4] = wp5;
  wa.src[5] = w3;   wa.dst[5] = wp6;

  // prep (weights, transposes, pads, mx=0)
  prep_all<<<9505, 256, 0, stream>>>(h2, h1, wa, h2t, Zt, mx);
  // eig path (writes Zt cols 160..163)
  maxd2_kernel<<<dim3(NPTS / 64, 8, NB), 256, 0, stream>>>(pc, mx);
  eigs_partial<<<dim3(NPTS / 32, 4, NB), 256, 0, stream>>>(pc, mx, part);
  eigs_finalize<<<NB * NPTS / 256, 256, 0, stream>>>(part, ew1, eb1, ew2, eb2, Zt);

  auto layerD = [&](const unsigned short* Wp, const unsigned short* X, unsigned short* Y,
                    int M, int Mp, int Kp, const float* g, const float* be) {
    gemm_mfma_t<0><<<dim3(64, Mp / 64, NB), 256, 0, stream>>>(Wp, X, a_, b_, Y, psum, psq,
                                                              M, Mp, Kp);
    bn_finalize<<<M, 256, 0, stream>>>(psum, psq, g, be, a_, b_);
  };
  auto layerF = [&](const unsigned short* Wp, const unsigned short* X, unsigned short* Y,
                    int M, int Mp, int Kp, const float* g, const float* be) {
    gemm_mfma_t<1><<<dim3(64, Mp / 64, NB), 256, 0, stream>>>(Wp, X, a_, b_, Y, psum, psq,
                                                              M, Mp, Kp);
    bn_finalize<<<M, 256, 0, stream>>>(psum, psq, g, be, a_, b_);
  };

  // dg chain (conv biases cancel under BN mean subtraction)
  layerD(wp1, h2t, yA, 256, 256, 1024, dgg1, dgbe1);  // L1
  layerF(wp2, yA, yB, 64, 64, 256, dgg2, dgbe2);      // L2 (BN of L1 in staging)
  layerF(wp3, yB, yA, 32, 64, 64, dgg3, dgbe3);       // L3
  f2_apply<<<NB * NPTS * 8 / 256, 256, 0, stream>>>(yA, a_, b_, Zt);  // f2 -> Zt
  // head chain
  layerD(wp4, Zt, yB, 512, 512, 192, g1, be1);        // L4
  layerF(wp5, yB, yA, 256, 256, 512, g2, be2);        // L5
  layerF(wp6, yA, yB, 128, 128, 256, g3, be3);        // L6
  out_final<<<1048, 256, 0, stream>>>(yB, a_, b_, pc, out);
}